// Round 9
// baseline (1212.997 us; speedup 1.0000x reference)
//
#include <hip/hip_runtime.h>
#include <hip/hip_bf16.h>
#include <stdint.h>

#define NN 100000
#define DD 256
#define EE 1600000
#define NB 391   // ceil(NN/256)

typedef short s16x8 __attribute__((ext_vector_type(8)));
typedef float f32x4 __attribute__((ext_vector_type(4)));

__device__ __forceinline__ unsigned short f2bf(float f) {
    union { float f; unsigned int u; } un; un.f = f;
    unsigned int u = un.u;
    unsigned int r = u + 0x7fffu + ((u >> 16) & 1u);  // RNE
    return (unsigned short)(r >> 16);
}
__device__ __forceinline__ float bf2f(unsigned short s) {
    union { unsigned int u; float f; } c; c.u = (unsigned int)s << 16; return c.f;
}

// ---- all 6 weights -> MFMA B-fragment order (one launch)
__global__ void k_wconv6(const float* __restrict__ W0, const float* __restrict__ W1,
                         const float* __restrict__ W2, const float* __restrict__ W3,
                         const float* __restrict__ W4, const float* __restrict__ W5,
                         unsigned short* __restrict__ Wf) {
    int wi = blockIdx.x >> 8;
    const float* W = wi == 0 ? W0 : wi == 1 ? W1 : wi == 2 ? W2 :
                     wi == 3 ? W3 : wi == 4 ? W4 : W5;
    int t = (blockIdx.x & 255) * 256 + threadIdx.x;   // 0..65535
    int j = t & 7;
    int l = (t >> 3) & 63;
    int c = (t >> 9) & 15;
    int s = t >> 13;
    int k   = s * 32 + (l >> 4) * 8 + j;
    int col = c * 16 + (l & 15);
    Wf[wi * 65536 + t] = f2bf(W[k * 256 + col]);
}

// ================= CSR build =================
__global__ void k_deghist(const int* __restrict__ dst, int* __restrict__ deg) {
    int e = blockIdx.x * 256 + threadIdx.x;
    atomicAdd(&deg[dst[e]], 1);
}

__global__ void k_blocksum(const int* __restrict__ deg, int* __restrict__ bsum) {
    __shared__ int s[256];
    int t = blockIdx.x * 256 + threadIdx.x;
    s[threadIdx.x] = (t < NN) ? deg[t] : 0;
    __syncthreads();
    for (int off = 128; off > 0; off >>= 1) {
        if (threadIdx.x < off) s[threadIdx.x] += s[threadIdx.x + off];
        __syncthreads();
    }
    if (threadIdx.x == 0) bsum[blockIdx.x] = s[0];
}

__global__ void k_scanb(const int* __restrict__ bsum, int* __restrict__ boff,
                        int* __restrict__ rowptr) {
    __shared__ int s[512];
    int tid = threadIdx.x;
    s[tid] = (tid < NB) ? bsum[tid] : 0;
    __syncthreads();
    for (int off = 1; off < 512; off <<= 1) {
        int x = 0;
        if (tid >= off) x = s[tid - off];
        __syncthreads();
        if (tid >= off) s[tid] += x;
        __syncthreads();
    }
    if (tid < NB) boff[tid] = (tid > 0) ? s[tid - 1] : 0;
    if (tid == 0) rowptr[NN] = EE;
}

__global__ void k_finalscan(const int* __restrict__ deg, const int* __restrict__ boff,
                            int* __restrict__ rowptr) {
    __shared__ int s[256];
    int tid = threadIdx.x;
    int t = blockIdx.x * 256 + tid;
    int v = (t < NN) ? deg[t] : 0;
    s[tid] = v;
    __syncthreads();
    for (int off = 1; off < 256; off <<= 1) {
        int x = 0;
        if (tid >= off) x = s[tid - off];
        __syncthreads();
        if (tid >= off) s[tid] += x;
        __syncthreads();
    }
    if (t < NN) rowptr[t] = boff[blockIdx.x] + s[tid] - v;  // exclusive
}

__global__ void k_fill(const int* __restrict__ src, const int* __restrict__ dst,
                       const int* __restrict__ rowptr, int* __restrict__ cur,
                       int* __restrict__ eidx) {
    int e = blockIdx.x * 256 + threadIdx.x;
    int d = dst[e];
    int pos = atomicAdd(&cur[d], 1);
    eidx[rowptr[d] + pos] = src[e];
}

// ================= fused gather + GEMM1 + stats (16-node tile, 128 thr) ==========
// Block: 16 nodes, 2 waves; wave gathers 8 nodes (full 512B rows, 8-deep ILP)
// into the 8KB swizzled LDS A-tile, then MFMA (wave = 128-col half),
// writes z1 bf16 + fused stats.  LDS 10KB -> high blocks/CU.
// MODE 0: f32 h input, no BN.  MODE 1: bf16 raw-z input, fused BN+ReLU.
template<int MODE>
__launch_bounds__(128)
__global__ void k_gathmm(const void* __restrict__ hv, const int* __restrict__ rowptr,
                         const int* __restrict__ eidx,
                         const float* __restrict__ s1, const float* __restrict__ s2,
                         const float* __restrict__ g, const float* __restrict__ be,
                         const unsigned short* __restrict__ Wf,
                         const float* __restrict__ bias,
                         unsigned short* __restrict__ C,
                         float* __restrict__ s1o, float* __restrict__ s2o) {
    __shared__ s16x8 Al[512];    // 16 rows x 256 cols bf16 = 8 KB, XOR-swizzled
    __shared__ float sbn[512];
    const int tid = threadIdx.x;
    const int wave = tid >> 6;          // 0..1
    const int lane = tid & 63;
    const int base_row = blockIdx.x * 16;

    #pragma unroll
    for (int i = tid; i < 512; i += 128) sbn[i] = 0.f;

    // BN constants for this lane's 4 columns (MODE 1)
    float kk[4], sh[4];
    if constexpr (MODE == 1) {
        int c0 = lane * 4;
        float4 s1v = *(const float4*)(s1 + c0);
        float4 s2v = *(const float4*)(s2 + c0);
        float4 gv  = *(const float4*)(g + c0);
        float4 bev = *(const float4*)(be + c0);
        float m, var;
        m = s1v.x * (1.f/NN); var = s2v.x * (1.f/NN) - m*m; kk[0] = rsqrtf(var+1e-5f)*gv.x; sh[0] = bev.x - m*kk[0];
        m = s1v.y * (1.f/NN); var = s2v.y * (1.f/NN) - m*m; kk[1] = rsqrtf(var+1e-5f)*gv.y; sh[1] = bev.y - m*kk[1];
        m = s1v.z * (1.f/NN); var = s2v.z * (1.f/NN) - m*m; kk[2] = rsqrtf(var+1e-5f)*gv.z; sh[2] = bev.z - m*kk[2];
        m = s1v.w * (1.f/NN); var = s2v.w * (1.f/NN) - m*m; kk[3] = rsqrtf(var+1e-5f)*gv.w; sh[3] = bev.w - m*kk[3];
    }

    // ---- Phase A: gather 8 nodes per wave into LDS
    for (int j = 0; j < 8; j++) {
        int row = wave * 8 + j;
        int node = base_row + row;          // NN = 6250*16 exactly, no tail
        float4 acc = make_float4(0.f, 0.f, 0.f, 0.f);
        {
            int beg = rowptr[node];
            int end = rowptr[node + 1];
            if constexpr (MODE == 0) {
                const float4* h = (const float4*)hv;
                acc = h[(size_t)node * 64 + lane];
                int i = beg;
                for (; i + 8 <= end; i += 8) {
                    int idx[8];
                    #pragma unroll
                    for (int q = 0; q < 8; q++) idx[q] = eidx[i + q];
                    float4 v[8];
                    #pragma unroll
                    for (int q = 0; q < 8; q++) v[q] = h[(size_t)idx[q] * 64 + lane];
                    #pragma unroll
                    for (int q = 0; q < 8; q++) {
                        acc.x += v[q].x; acc.y += v[q].y; acc.z += v[q].z; acc.w += v[q].w;
                    }
                }
                for (; i + 4 <= end; i += 4) {
                    int idx[4];
                    #pragma unroll
                    for (int q = 0; q < 4; q++) idx[q] = eidx[i + q];
                    float4 v[4];
                    #pragma unroll
                    for (int q = 0; q < 4; q++) v[q] = h[(size_t)idx[q] * 64 + lane];
                    #pragma unroll
                    for (int q = 0; q < 4; q++) {
                        acc.x += v[q].x; acc.y += v[q].y; acc.z += v[q].z; acc.w += v[q].w;
                    }
                }
                for (; i < end; i++) {
                    float4 v = h[(size_t)eidx[i] * 64 + lane];
                    acc.x += v.x; acc.y += v.y; acc.z += v.z; acc.w += v.w;
                }
            } else {
                const ushort4* h = (const ushort4*)hv;
                ushort4 u = h[(size_t)node * 64 + lane];
                acc.x = fmaxf(bf2f(u.x) * kk[0] + sh[0], 0.f);
                acc.y = fmaxf(bf2f(u.y) * kk[1] + sh[1], 0.f);
                acc.z = fmaxf(bf2f(u.z) * kk[2] + sh[2], 0.f);
                acc.w = fmaxf(bf2f(u.w) * kk[3] + sh[3], 0.f);
                int i = beg;
                for (; i + 8 <= end; i += 8) {
                    int idx[8];
                    #pragma unroll
                    for (int q = 0; q < 8; q++) idx[q] = eidx[i + q];
                    ushort4 v[8];
                    #pragma unroll
                    for (int q = 0; q < 8; q++) v[q] = h[(size_t)idx[q] * 64 + lane];
                    #pragma unroll
                    for (int q = 0; q < 8; q++) {
                        acc.x += fmaxf(bf2f(v[q].x) * kk[0] + sh[0], 0.f);
                        acc.y += fmaxf(bf2f(v[q].y) * kk[1] + sh[1], 0.f);
                        acc.z += fmaxf(bf2f(v[q].z) * kk[2] + sh[2], 0.f);
                        acc.w += fmaxf(bf2f(v[q].w) * kk[3] + sh[3], 0.f);
                    }
                }
                for (; i + 4 <= end; i += 4) {
                    int idx[4];
                    #pragma unroll
                    for (int q = 0; q < 4; q++) idx[q] = eidx[i + q];
                    ushort4 v[4];
                    #pragma unroll
                    for (int q = 0; q < 4; q++) v[q] = h[(size_t)idx[q] * 64 + lane];
                    #pragma unroll
                    for (int q = 0; q < 4; q++) {
                        acc.x += fmaxf(bf2f(v[q].x) * kk[0] + sh[0], 0.f);
                        acc.y += fmaxf(bf2f(v[q].y) * kk[1] + sh[1], 0.f);
                        acc.z += fmaxf(bf2f(v[q].z) * kk[2] + sh[2], 0.f);
                        acc.w += fmaxf(bf2f(v[q].w) * kk[3] + sh[3], 0.f);
                    }
                }
                for (; i < end; i++) {
                    ushort4 a = h[(size_t)eidx[i] * 64 + lane];
                    acc.x += fmaxf(bf2f(a.x) * kk[0] + sh[0], 0.f);
                    acc.y += fmaxf(bf2f(a.y) * kk[1] + sh[1], 0.f);
                    acc.z += fmaxf(bf2f(a.z) * kk[2] + sh[2], 0.f);
                    acc.w += fmaxf(bf2f(a.w) * kk[3] + sh[3], 0.f);
                }
            }
        }
        ushort4 o;
        o.x = f2bf(acc.x); o.y = f2bf(acc.y); o.z = f2bf(acc.z); o.w = f2bf(acc.w);
        int byte = (row * 512 + lane * 8) ^ ((row & 7) << 4);
        *(ushort4*)((char*)Al + byte) = o;
    }
    __syncthreads();

    // ---- Phase B: MFMA (wave = 128-col half) + bias + bf16 store + stats
    f32x4 acc[8];
    #pragma unroll
    for (int c = 0; c < 8; c++)
        acc[c] = (f32x4){0.f, 0.f, 0.f, 0.f};

    #pragma unroll
    for (int s = 0; s < 8; s++) {
        s16x8 a, b[8];
        {
            int row = lane & 15;
            int koff = s * 32 + (lane >> 4) * 8;
            int byte = (row * 512 + koff * 2) ^ ((row & 7) << 4);
            a = Al[byte >> 4];
        }
        const unsigned short* wp = Wf + (size_t)((s * 16 + wave * 8) * 64 + lane) * 8;
        #pragma unroll
        for (int c = 0; c < 8; c++)
            b[c] = *(const s16x8*)(wp + (size_t)c * 512);
        #pragma unroll
        for (int c = 0; c < 8; c++)
            acc[c] = __builtin_amdgcn_mfma_f32_16x16x32_bf16(a, b[c], acc[c], 0, 0, 0);
    }

    {
        int row0 = base_row + (lane >> 4) * 4;
        #pragma unroll
        for (int c = 0; c < 8; c++) {
            int col = wave * 128 + c * 16 + (lane & 15);
            float bv = bias[col];
            float p1 = 0.f, p2 = 0.f;
            #pragma unroll
            for (int r = 0; r < 4; r++) {
                int row = row0 + r;
                float v = acc[c][r] + bv;
                C[(size_t)row * 256 + col] = f2bf(v);
                p1 += v; p2 += v * v;
            }
            p1 += __shfl_xor(p1, 16); p1 += __shfl_xor(p1, 32);
            p2 += __shfl_xor(p2, 16); p2 += __shfl_xor(p2, 32);
            if (lane < 16) {
                atomicAdd(&sbn[col], p1);
                atomicAdd(&sbn[col + 256], p2);
            }
        }
    }
    __syncthreads();
    #pragma unroll
    for (int i = tid; i < 256; i += 128) {
        atomicAdd(&s1o[i], sbn[i]);
        atomicAdd(&s2o[i], sbn[i + 256]);
    }
}

// ================= GEMM (bf16 A + optional BN staging) =================
template<bool BNSTAGE, bool OUTBF16, bool STATS>
__launch_bounds__(256)
__global__ void k_gemm(const unsigned short* __restrict__ Av,
                       const unsigned short* __restrict__ Wf,
                       const float* __restrict__ bias,
                       const float* __restrict__ s1, const float* __restrict__ s2,
                       const float* __restrict__ g, const float* __restrict__ be,
                       void* __restrict__ Cv,
                       float* __restrict__ s1o, float* __restrict__ s2o, int M) {
    __shared__ s16x8 Al[2048];
    __shared__ float sbn[512];
    const int tid = threadIdx.x;
    const int base_row = blockIdx.x * 64;

    if constexpr (STATS) {
        sbn[tid] = 0.f; sbn[tid + 256] = 0.f;
    }

    #pragma unroll
    for (int i = 0; i < 8; i++) {
        int chunk = tid + i * 256;
        int row = chunk >> 5;
        int k0  = (chunk & 31) * 8;
        int gr = base_row + row;
        s16x8 sv;
        if (gr < M)
            sv = *(const s16x8*)(Av + (size_t)gr * 256 + k0);
        else
            sv = (s16x8){0,0,0,0,0,0,0,0};
        if constexpr (BNSTAGE) {
            #pragma unroll
            for (int j = 0; j < 8; j++) {
                float m  = s1[k0+j] * (1.f/NN);
                float var = s2[k0+j] * (1.f/NN) - m*m;
                float kk = rsqrtf(var + 1e-5f) * g[k0+j];
                float shv = be[k0+j] - m * kk;
                float f = fmaxf(bf2f((unsigned short)sv[j]) * kk + shv, 0.f);
                sv[j] = (short)f2bf(f);
            }
        }
        int byte = (row * 512 + k0 * 2) ^ ((row & 7) << 4);
        Al[byte >> 4] = sv;
    }
    __syncthreads();

    const int lane = tid & 63;
    const int w = tid >> 6;
    const int wr = w >> 1;
    const int wc = w & 1;

    f32x4 acc[2][8];
    #pragma unroll
    for (int m = 0; m < 2; m++)
        #pragma unroll
        for (int c = 0; c < 8; c++)
            acc[m][c] = (f32x4){0.f, 0.f, 0.f, 0.f};

    #pragma unroll
    for (int s = 0; s < 8; s++) {
        s16x8 a[2], b[8];
        #pragma unroll
        for (int m = 0; m < 2; m++) {
            int row = wr * 32 + m * 16 + (lane & 15);
            int koff = s * 32 + (lane >> 4) * 8;
            int byte = (row * 512 + koff * 2) ^ ((row & 7) << 4);
            a[m] = Al[byte >> 4];
        }
        const unsigned short* wp = Wf + (size_t)((s * 16 + wc * 8) * 64 + lane) * 8;
        #pragma unroll
        for (int c = 0; c < 8; c++)
            b[c] = *(const s16x8*)(wp + (size_t)c * 512);
        #pragma unroll
        for (int m = 0; m < 2; m++)
            #pragma unroll
            for (int c = 0; c < 8; c++)
                acc[m][c] = __builtin_amdgcn_mfma_f32_16x16x32_bf16(a[m], b[c], acc[m][c], 0, 0, 0);
    }

    #pragma unroll
    for (int m = 0; m < 2; m++) {
        int row0 = base_row + wr * 32 + m * 16 + (lane >> 4) * 4;
        #pragma unroll
        for (int c = 0; c < 8; c++) {
            int col = wc * 128 + c * 16 + (lane & 15);
            float bv = bias[col];
            float p1 = 0.f, p2 = 0.f;
            #pragma unroll
            for (int r = 0; r < 4; r++) {
                int row = row0 + r;
                if (row < M) {
                    float v = acc[m][c][r] + bv;
                    if constexpr (OUTBF16)
                        ((unsigned short*)Cv)[(size_t)row * 256 + col] = f2bf(v);
                    else
                        ((float*)Cv)[(size_t)row * 256 + col] = v;
                    if constexpr (STATS) { p1 += v; p2 += v * v; }
                }
            }
            if constexpr (STATS) {
                p1 += __shfl_xor(p1, 16); p1 += __shfl_xor(p1, 32);
                p2 += __shfl_xor(p2, 16); p2 += __shfl_xor(p2, 32);
                if (lane < 16) {
                    atomicAdd(&sbn[col], p1);
                    atomicAdd(&sbn[col + 256], p2);
                }
            }
        }
    }
    if constexpr (STATS) {
        __syncthreads();
        atomicAdd(&s1o[tid & 255], sbn[tid]);
        atomicAdd(&s2o[tid & 255], sbn[tid + 256]);
    }
}

extern "C" void kernel_launch(void* const* d_in, const int* in_sizes, int n_in,
                              void* d_out, int out_size, void* d_ws, size_t ws_size,
                              hipStream_t stream) {
    const float* x   = (const float*)d_in[0];
    const int*   src = (const int*)d_in[1];
    const int*   dst = (const int*)d_in[2];
    const float* W[6]    = { (const float*)d_in[3],  (const float*)d_in[7],
                             (const float*)d_in[11], (const float*)d_in[15],
                             (const float*)d_in[19], (const float*)d_in[23] };
    const float* Bias[6] = { (const float*)d_in[4],  (const float*)d_in[8],
                             (const float*)d_in[12], (const float*)d_in[16],
                             (const float*)d_in[20], (const float*)d_in[24] };
    const float* Gam[5]  = { (const float*)d_in[5],  (const float*)d_in[9],
                             (const float*)d_in[13], (const float*)d_in[17],
                             (const float*)d_in[21] };
    const float* Bet[5]  = { (const float*)d_in[6],  (const float*)d_in[10],
                             (const float*)d_in[14], (const float*)d_in[18],
                             (const float*)d_in[22] };

    char* ws = (char*)d_ws;
    unsigned short* Wf = (unsigned short*)ws;              // 786,432 B
    float* stats = (float*)(ws + 786432);                  // 10,240 B
    unsigned short* z1bf = (unsigned short*)(ws + (1 << 20));        // 51.2 MB
    unsigned short* z2bf = z1bf + (size_t)NN * DD;                   // 51.2 MB
    char* csr = ws + (1 << 20) + 102400000;
    int* rowptr = (int*)csr;
    int* deg    = (int*)(csr + 400128);
    int* cur    = (int*)(csr + 800128);
    int* bsum   = (int*)(csr + 1200128);
    int* boff   = (int*)(csr + 1202176);
    int* eidx   = (int*)(csr + 1204224);
    float* OUT = (float*)d_out;

    // ---- prep
    k_wconv6<<<1536, 256, 0, stream>>>(W[0], W[1], W[2], W[3], W[4], W[5], Wf);
    hipMemsetAsync(stats, 0, 5 * 512 * sizeof(float), stream);
    hipMemsetAsync(deg, 0, NN * sizeof(int), stream);
    hipMemsetAsync(cur, 0, NN * sizeof(int), stream);

    k_deghist<<<EE / 256, 256, 0, stream>>>(dst, deg);
    k_blocksum<<<NB, 256, 0, stream>>>(deg, bsum);
    k_scanb<<<1, 512, 0, stream>>>(bsum, boff, rowptr);
    k_finalscan<<<NB, 256, 0, stream>>>(deg, boff, rowptr);
    k_fill<<<EE / 256, 256, 0, stream>>>(src, dst, rowptr, cur, eidx);

    float* st[5];
    for (int i = 0; i < 5; i++) st[i] = stats + i * 512;

    // GEMM2: bf16 z1 + BN staged -> bf16 z2, fused stats
    auto gemm2 = [&](const unsigned short* A, int wi, int si, int so, unsigned short* Cb) {
        k_gemm<true, true, true><<<1563, 256, 0, stream>>>(
            A, Wf + (size_t)wi * 65536, Bias[wi], st[si], st[si] + 256, Gam[si], Bet[si],
            Cb, st[so], st[so] + 256, NN);
    };

    const int GMM = NN / 16;   // 6250 blocks, exact

    // ---- Layer 0 (h = x, f32): fused gather+GEMM1 -> z1 bf16 + stats0
    k_gathmm<0><<<GMM, 128, 0, stream>>>(x, rowptr, eidx,
                                         nullptr, nullptr, nullptr, nullptr,
                                         Wf + (size_t)0 * 65536, Bias[0],
                                         z1bf, st[0], st[0] + 256);
    gemm2(z1bf, 1, 0, 1, z2bf);

    // ---- Layer 1: fused gather(BN st1)+GEMM1(W2) -> z1 + stats2
    k_gathmm<1><<<GMM, 128, 0, stream>>>(z2bf, rowptr, eidx,
                                         st[1], st[1] + 256, Gam[1], Bet[1],
                                         Wf + (size_t)2 * 65536, Bias[2],
                                         z1bf, st[2], st[2] + 256);
    gemm2(z1bf, 3, 2, 3, z2bf);

    // ---- Layer 2: fused gather(BN st3)+GEMM1(W4) -> z1 + stats4
    k_gathmm<1><<<GMM, 128, 0, stream>>>(z2bf, rowptr, eidx,
                                         st[3], st[3] + 256, Gam[3], Bet[3],
                                         Wf + (size_t)4 * 65536, Bias[4],
                                         z1bf, st[4], st[4] + 256);
    // final: bf16 z1 + BN staged -> f32 OUT (no stats)
    k_gemm<true, false, false><<<1563, 256, 0, stream>>>(
        z1bf, Wf + (size_t)5 * 65536, Bias[5], st[4], st[4] + 256, Gam[4], Bet[4],
        OUT, nullptr, nullptr, NN);
}

// Round 10
// 987.214 us; speedup vs baseline: 1.2287x; 1.2287x over previous
//
#include <hip/hip_runtime.h>
#include <hip/hip_bf16.h>
#include <stdint.h>

#define NN 100000
#define DD 256
#define EE 1600000
#define NB 391   // ceil(NN/256)

typedef short s16x8 __attribute__((ext_vector_type(8)));
typedef float f32x4 __attribute__((ext_vector_type(4)));

__device__ __forceinline__ unsigned short f2bf(float f) {
    union { float f; unsigned int u; } un; un.f = f;
    unsigned int u = un.u;
    unsigned int r = u + 0x7fffu + ((u >> 16) & 1u);  // RNE
    return (unsigned short)(r >> 16);
}
__device__ __forceinline__ float bf2f(unsigned short s) {
    union { unsigned int u; float f; } c; c.u = (unsigned int)s << 16; return c.f;
}

// ---- all 6 weights -> MFMA B-fragment order (one launch)
__global__ void k_wconv6(const float* __restrict__ W0, const float* __restrict__ W1,
                         const float* __restrict__ W2, const float* __restrict__ W3,
                         const float* __restrict__ W4, const float* __restrict__ W5,
                         unsigned short* __restrict__ Wf) {
    int wi = blockIdx.x >> 8;
    const float* W = wi == 0 ? W0 : wi == 1 ? W1 : wi == 2 ? W2 :
                     wi == 3 ? W3 : wi == 4 ? W4 : W5;
    int t = (blockIdx.x & 255) * 256 + threadIdx.x;   // 0..65535
    int j = t & 7;
    int l = (t >> 3) & 63;
    int c = (t >> 9) & 15;
    int s = t >> 13;
    int k   = s * 32 + (l >> 4) * 8 + j;
    int col = c * 16 + (l & 15);
    Wf[wi * 65536 + t] = f2bf(W[k * 256 + col]);
}

// ================= CSR build =================
__global__ void k_deghist(const int* __restrict__ dst, int* __restrict__ deg) {
    int e = blockIdx.x * 256 + threadIdx.x;
    atomicAdd(&deg[dst[e]], 1);
}

__global__ void k_blocksum(const int* __restrict__ deg, int* __restrict__ bsum) {
    __shared__ int s[256];
    int t = blockIdx.x * 256 + threadIdx.x;
    s[threadIdx.x] = (t < NN) ? deg[t] : 0;
    __syncthreads();
    for (int off = 128; off > 0; off >>= 1) {
        if (threadIdx.x < off) s[threadIdx.x] += s[threadIdx.x + off];
        __syncthreads();
    }
    if (threadIdx.x == 0) bsum[blockIdx.x] = s[0];
}

__global__ void k_scanb(const int* __restrict__ bsum, int* __restrict__ boff,
                        int* __restrict__ rowptr) {
    __shared__ int s[512];
    int tid = threadIdx.x;
    s[tid] = (tid < NB) ? bsum[tid] : 0;
    __syncthreads();
    for (int off = 1; off < 512; off <<= 1) {
        int x = 0;
        if (tid >= off) x = s[tid - off];
        __syncthreads();
        if (tid >= off) s[tid] += x;
        __syncthreads();
    }
    if (tid < NB) boff[tid] = (tid > 0) ? s[tid - 1] : 0;
    if (tid == 0) rowptr[NN] = EE;
}

__global__ void k_finalscan(const int* __restrict__ deg, const int* __restrict__ boff,
                            int* __restrict__ rowptr) {
    __shared__ int s[256];
    int tid = threadIdx.x;
    int t = blockIdx.x * 256 + tid;
    int v = (t < NN) ? deg[t] : 0;
    s[tid] = v;
    __syncthreads();
    for (int off = 1; off < 256; off <<= 1) {
        int x = 0;
        if (tid >= off) x = s[tid - off];
        __syncthreads();
        if (tid >= off) s[tid] += x;
        __syncthreads();
    }
    if (t < NN) rowptr[t] = boff[blockIdx.x] + s[tid] - v;  // exclusive
}

__global__ void k_fill(const int* __restrict__ src, const int* __restrict__ dst,
                       const int* __restrict__ rowptr, int* __restrict__ cur,
                       int* __restrict__ eidx) {
    int e = blockIdx.x * 256 + threadIdx.x;
    int d = dst[e];
    int pos = atomicAdd(&cur[d], 1);
    eidx[rowptr[d] + pos] = src[e];
}

// ===== fused gather + GEMM1 + stats (32-node tile, 512 thr / 8 waves) =====
// Wave gathers 4 nodes (full 512B rows, 8-deep ILP) into the 16KB swizzled
// LDS A-tile; MFMA phase: wave owns a 32-col slice (acc[2][2]).
// LDS 18KB but only 2.3KB/wave -> wave-slot bound, not LDS bound.
// MODE 0: f32 h input, no BN.  MODE 1: bf16 raw-z input, fused BN+ReLU.
template<int MODE>
__launch_bounds__(512)
__global__ void k_gathmm(const void* __restrict__ hv, const int* __restrict__ rowptr,
                         const int* __restrict__ eidx,
                         const float* __restrict__ s1, const float* __restrict__ s2,
                         const float* __restrict__ g, const float* __restrict__ be,
                         const unsigned short* __restrict__ Wf,
                         const float* __restrict__ bias,
                         unsigned short* __restrict__ C,
                         float* __restrict__ s1o, float* __restrict__ s2o) {
    __shared__ s16x8 Al[1024];   // 32 rows x 256 cols bf16 = 16 KB, XOR-swizzled
    __shared__ float sbn[512];
    const int tid = threadIdx.x;
    const int wave = tid >> 6;          // 0..7
    const int lane = tid & 63;
    const int base_row = blockIdx.x * 32;   // NN = 3125*32 exactly

    sbn[tid] = 0.f;

    // BN constants for this lane's 4 columns (MODE 1)
    float kk[4], sh[4];
    if constexpr (MODE == 1) {
        int c0 = lane * 4;
        float4 s1v = *(const float4*)(s1 + c0);
        float4 s2v = *(const float4*)(s2 + c0);
        float4 gv  = *(const float4*)(g + c0);
        float4 bev = *(const float4*)(be + c0);
        float m, var;
        m = s1v.x * (1.f/NN); var = s2v.x * (1.f/NN) - m*m; kk[0] = rsqrtf(var+1e-5f)*gv.x; sh[0] = bev.x - m*kk[0];
        m = s1v.y * (1.f/NN); var = s2v.y * (1.f/NN) - m*m; kk[1] = rsqrtf(var+1e-5f)*gv.y; sh[1] = bev.y - m*kk[1];
        m = s1v.z * (1.f/NN); var = s2v.z * (1.f/NN) - m*m; kk[2] = rsqrtf(var+1e-5f)*gv.z; sh[2] = bev.z - m*kk[2];
        m = s1v.w * (1.f/NN); var = s2v.w * (1.f/NN) - m*m; kk[3] = rsqrtf(var+1e-5f)*gv.w; sh[3] = bev.w - m*kk[3];
    }

    // ---- Phase A: gather 4 nodes per wave into LDS
    for (int j = 0; j < 4; j++) {
        int row = wave * 4 + j;
        int node = base_row + row;
        float4 acc;
        int beg = rowptr[node];
        int end = rowptr[node + 1];
        if constexpr (MODE == 0) {
            const float4* h = (const float4*)hv;
            acc = h[(size_t)node * 64 + lane];
            int i = beg;
            for (; i + 8 <= end; i += 8) {
                int idx[8];
                #pragma unroll
                for (int q = 0; q < 8; q++) idx[q] = eidx[i + q];
                float4 v[8];
                #pragma unroll
                for (int q = 0; q < 8; q++) v[q] = h[(size_t)idx[q] * 64 + lane];
                #pragma unroll
                for (int q = 0; q < 8; q++) {
                    acc.x += v[q].x; acc.y += v[q].y; acc.z += v[q].z; acc.w += v[q].w;
                }
            }
            for (; i + 4 <= end; i += 4) {
                int idx[4];
                #pragma unroll
                for (int q = 0; q < 4; q++) idx[q] = eidx[i + q];
                float4 v[4];
                #pragma unroll
                for (int q = 0; q < 4; q++) v[q] = h[(size_t)idx[q] * 64 + lane];
                #pragma unroll
                for (int q = 0; q < 4; q++) {
                    acc.x += v[q].x; acc.y += v[q].y; acc.z += v[q].z; acc.w += v[q].w;
                }
            }
            for (; i < end; i++) {
                float4 v = h[(size_t)eidx[i] * 64 + lane];
                acc.x += v.x; acc.y += v.y; acc.z += v.z; acc.w += v.w;
            }
        } else {
            const ushort4* h = (const ushort4*)hv;
            ushort4 u = h[(size_t)node * 64 + lane];
            acc.x = fmaxf(bf2f(u.x) * kk[0] + sh[0], 0.f);
            acc.y = fmaxf(bf2f(u.y) * kk[1] + sh[1], 0.f);
            acc.z = fmaxf(bf2f(u.z) * kk[2] + sh[2], 0.f);
            acc.w = fmaxf(bf2f(u.w) * kk[3] + sh[3], 0.f);
            int i = beg;
            for (; i + 8 <= end; i += 8) {
                int idx[8];
                #pragma unroll
                for (int q = 0; q < 8; q++) idx[q] = eidx[i + q];
                ushort4 v[8];
                #pragma unroll
                for (int q = 0; q < 8; q++) v[q] = h[(size_t)idx[q] * 64 + lane];
                #pragma unroll
                for (int q = 0; q < 8; q++) {
                    acc.x += fmaxf(bf2f(v[q].x) * kk[0] + sh[0], 0.f);
                    acc.y += fmaxf(bf2f(v[q].y) * kk[1] + sh[1], 0.f);
                    acc.z += fmaxf(bf2f(v[q].z) * kk[2] + sh[2], 0.f);
                    acc.w += fmaxf(bf2f(v[q].w) * kk[3] + sh[3], 0.f);
                }
            }
            for (; i + 4 <= end; i += 4) {
                int idx[4];
                #pragma unroll
                for (int q = 0; q < 4; q++) idx[q] = eidx[i + q];
                ushort4 v[4];
                #pragma unroll
                for (int q = 0; q < 4; q++) v[q] = h[(size_t)idx[q] * 64 + lane];
                #pragma unroll
                for (int q = 0; q < 4; q++) {
                    acc.x += fmaxf(bf2f(v[q].x) * kk[0] + sh[0], 0.f);
                    acc.y += fmaxf(bf2f(v[q].y) * kk[1] + sh[1], 0.f);
                    acc.z += fmaxf(bf2f(v[q].z) * kk[2] + sh[2], 0.f);
                    acc.w += fmaxf(bf2f(v[q].w) * kk[3] + sh[3], 0.f);
                }
            }
            for (; i < end; i++) {
                ushort4 a = h[(size_t)eidx[i] * 64 + lane];
                acc.x += fmaxf(bf2f(a.x) * kk[0] + sh[0], 0.f);
                acc.y += fmaxf(bf2f(a.y) * kk[1] + sh[1], 0.f);
                acc.z += fmaxf(bf2f(a.z) * kk[2] + sh[2], 0.f);
                acc.w += fmaxf(bf2f(a.w) * kk[3] + sh[3], 0.f);
            }
        }
        ushort4 o;
        o.x = f2bf(acc.x); o.y = f2bf(acc.y); o.z = f2bf(acc.z); o.w = f2bf(acc.w);
        int byte = (row * 512 + lane * 8) ^ ((row & 7) << 4);
        *(ushort4*)((char*)Al + byte) = o;
    }
    __syncthreads();

    // ---- Phase B: MFMA (wave = 32-col slice) + bias + bf16 store + stats
    f32x4 acc[2][2];
    #pragma unroll
    for (int m = 0; m < 2; m++)
        #pragma unroll
        for (int c = 0; c < 2; c++)
            acc[m][c] = (f32x4){0.f, 0.f, 0.f, 0.f};

    #pragma unroll
    for (int s = 0; s < 8; s++) {
        s16x8 a[2], b[2];
        #pragma unroll
        for (int m = 0; m < 2; m++) {
            int row = m * 16 + (lane & 15);
            int koff = s * 32 + (lane >> 4) * 8;
            int byte = (row * 512 + koff * 2) ^ ((row & 7) << 4);
            a[m] = Al[byte >> 4];
        }
        const unsigned short* wp = Wf + (size_t)((s * 16 + wave * 2) * 64 + lane) * 8;
        #pragma unroll
        for (int c = 0; c < 2; c++)
            b[c] = *(const s16x8*)(wp + (size_t)c * 512);
        #pragma unroll
        for (int m = 0; m < 2; m++)
            #pragma unroll
            for (int c = 0; c < 2; c++)
                acc[m][c] = __builtin_amdgcn_mfma_f32_16x16x32_bf16(a[m], b[c], acc[m][c], 0, 0, 0);
    }

    #pragma unroll
    for (int m = 0; m < 2; m++) {
        int row0 = base_row + m * 16 + (lane >> 4) * 4;
        #pragma unroll
        for (int c = 0; c < 2; c++) {
            int col = wave * 32 + c * 16 + (lane & 15);
            float bv = bias[col];
            float p1 = 0.f, p2 = 0.f;
            #pragma unroll
            for (int r = 0; r < 4; r++) {
                int row = row0 + r;
                float v = acc[m][c][r] + bv;
                C[(size_t)row * 256 + col] = f2bf(v);
                p1 += v; p2 += v * v;
            }
            p1 += __shfl_xor(p1, 16); p1 += __shfl_xor(p1, 32);
            p2 += __shfl_xor(p2, 16); p2 += __shfl_xor(p2, 32);
            if (lane < 16) {
                atomicAdd(&sbn[col], p1);
                atomicAdd(&sbn[col + 256], p2);
            }
        }
    }
    __syncthreads();
    if (tid < 256) {
        atomicAdd(&s1o[tid], sbn[tid]);
        atomicAdd(&s2o[tid], sbn[tid + 256]);
    }
}

// ================= GEMM (bf16 A + optional BN staging) =================
template<bool BNSTAGE, bool OUTBF16, bool STATS>
__launch_bounds__(256)
__global__ void k_gemm(const unsigned short* __restrict__ Av,
                       const unsigned short* __restrict__ Wf,
                       const float* __restrict__ bias,
                       const float* __restrict__ s1, const float* __restrict__ s2,
                       const float* __restrict__ g, const float* __restrict__ be,
                       void* __restrict__ Cv,
                       float* __restrict__ s1o, float* __restrict__ s2o, int M) {
    __shared__ s16x8 Al[2048];
    __shared__ float sbn[512];
    const int tid = threadIdx.x;
    const int base_row = blockIdx.x * 64;

    if constexpr (STATS) {
        sbn[tid] = 0.f; sbn[tid + 256] = 0.f;
    }

    #pragma unroll
    for (int i = 0; i < 8; i++) {
        int chunk = tid + i * 256;
        int row = chunk >> 5;
        int k0  = (chunk & 31) * 8;
        int gr = base_row + row;
        s16x8 sv;
        if (gr < M)
            sv = *(const s16x8*)(Av + (size_t)gr * 256 + k0);
        else
            sv = (s16x8){0,0,0,0,0,0,0,0};
        if constexpr (BNSTAGE) {
            #pragma unroll
            for (int j = 0; j < 8; j++) {
                float m  = s1[k0+j] * (1.f/NN);
                float var = s2[k0+j] * (1.f/NN) - m*m;
                float kk = rsqrtf(var + 1e-5f) * g[k0+j];
                float shv = be[k0+j] - m * kk;
                float f = fmaxf(bf2f((unsigned short)sv[j]) * kk + shv, 0.f);
                sv[j] = (short)f2bf(f);
            }
        }
        int byte = (row * 512 + k0 * 2) ^ ((row & 7) << 4);
        Al[byte >> 4] = sv;
    }
    __syncthreads();

    const int lane = tid & 63;
    const int w = tid >> 6;
    const int wr = w >> 1;
    const int wc = w & 1;

    f32x4 acc[2][8];
    #pragma unroll
    for (int m = 0; m < 2; m++)
        #pragma unroll
        for (int c = 0; c < 8; c++)
            acc[m][c] = (f32x4){0.f, 0.f, 0.f, 0.f};

    #pragma unroll
    for (int s = 0; s < 8; s++) {
        s16x8 a[2], b[8];
        #pragma unroll
        for (int m = 0; m < 2; m++) {
            int row = wr * 32 + m * 16 + (lane & 15);
            int koff = s * 32 + (lane >> 4) * 8;
            int byte = (row * 512 + koff * 2) ^ ((row & 7) << 4);
            a[m] = Al[byte >> 4];
        }
        const unsigned short* wp = Wf + (size_t)((s * 16 + wc * 8) * 64 + lane) * 8;
        #pragma unroll
        for (int c = 0; c < 8; c++)
            b[c] = *(const s16x8*)(wp + (size_t)c * 512);
        #pragma unroll
        for (int m = 0; m < 2; m++)
            #pragma unroll
            for (int c = 0; c < 8; c++)
                acc[m][c] = __builtin_amdgcn_mfma_f32_16x16x32_bf16(a[m], b[c], acc[m][c], 0, 0, 0);
    }

    #pragma unroll
    for (int m = 0; m < 2; m++) {
        int row0 = base_row + wr * 32 + m * 16 + (lane >> 4) * 4;
        #pragma unroll
        for (int c = 0; c < 8; c++) {
            int col = wc * 128 + c * 16 + (lane & 15);
            float bv = bias[col];
            float p1 = 0.f, p2 = 0.f;
            #pragma unroll
            for (int r = 0; r < 4; r++) {
                int row = row0 + r;
                if (row < M) {
                    float v = acc[m][c][r] + bv;
                    if constexpr (OUTBF16)
                        ((unsigned short*)Cv)[(size_t)row * 256 + col] = f2bf(v);
                    else
                        ((float*)Cv)[(size_t)row * 256 + col] = v;
                    if constexpr (STATS) { p1 += v; p2 += v * v; }
                }
            }
            if constexpr (STATS) {
                p1 += __shfl_xor(p1, 16); p1 += __shfl_xor(p1, 32);
                p2 += __shfl_xor(p2, 16); p2 += __shfl_xor(p2, 32);
                if (lane < 16) {
                    atomicAdd(&sbn[col], p1);
                    atomicAdd(&sbn[col + 256], p2);
                }
            }
        }
    }
    if constexpr (STATS) {
        __syncthreads();
        atomicAdd(&s1o[tid & 255], sbn[tid]);
        atomicAdd(&s2o[tid & 255], sbn[tid + 256]);
    }
}

extern "C" void kernel_launch(void* const* d_in, const int* in_sizes, int n_in,
                              void* d_out, int out_size, void* d_ws, size_t ws_size,
                              hipStream_t stream) {
    const float* x   = (const float*)d_in[0];
    const int*   src = (const int*)d_in[1];
    const int*   dst = (const int*)d_in[2];
    const float* W[6]    = { (const float*)d_in[3],  (const float*)d_in[7],
                             (const float*)d_in[11], (const float*)d_in[15],
                             (const float*)d_in[19], (const float*)d_in[23] };
    const float* Bias[6] = { (const float*)d_in[4],  (const float*)d_in[8],
                             (const float*)d_in[12], (const float*)d_in[16],
                             (const float*)d_in[20], (const float*)d_in[24] };
    const float* Gam[5]  = { (const float*)d_in[5],  (const float*)d_in[9],
                             (const float*)d_in[13], (const float*)d_in[17],
                             (const float*)d_in[21] };
    const float* Bet[5]  = { (const float*)d_in[6],  (const float*)d_in[10],
                             (const float*)d_in[14], (const float*)d_in[18],
                             (const float*)d_in[22] };

    char* ws = (char*)d_ws;
    unsigned short* Wf = (unsigned short*)ws;              // 786,432 B
    float* stats = (float*)(ws + 786432);                  // 10,240 B
    unsigned short* z1bf = (unsigned short*)(ws + (1 << 20));        // 51.2 MB
    unsigned short* z2bf = z1bf + (size_t)NN * DD;                   // 51.2 MB
    char* csr = ws + (1 << 20) + 102400000;
    int* rowptr = (int*)csr;
    int* deg    = (int*)(csr + 400128);
    int* cur    = (int*)(csr + 800128);
    int* bsum   = (int*)(csr + 1200128);
    int* boff   = (int*)(csr + 1202176);
    int* eidx   = (int*)(csr + 1204224);
    float* OUT = (float*)d_out;

    // ---- prep
    k_wconv6<<<1536, 256, 0, stream>>>(W[0], W[1], W[2], W[3], W[4], W[5], Wf);
    hipMemsetAsync(stats, 0, 5 * 512 * sizeof(float), stream);
    hipMemsetAsync(deg, 0, NN * sizeof(int), stream);
    hipMemsetAsync(cur, 0, NN * sizeof(int), stream);

    k_deghist<<<EE / 256, 256, 0, stream>>>(dst, deg);
    k_blocksum<<<NB, 256, 0, stream>>>(deg, bsum);
    k_scanb<<<1, 512, 0, stream>>>(bsum, boff, rowptr);
    k_finalscan<<<NB, 256, 0, stream>>>(deg, boff, rowptr);
    k_fill<<<EE / 256, 256, 0, stream>>>(src, dst, rowptr, cur, eidx);

    float* st[5];
    for (int i = 0; i < 5; i++) st[i] = stats + i * 512;

    // GEMM2: bf16 z1 + BN staged -> bf16 z2, fused stats
    auto gemm2 = [&](const unsigned short* A, int wi, int si, int so, unsigned short* Cb) {
        k_gemm<true, true, true><<<1563, 256, 0, stream>>>(
            A, Wf + (size_t)wi * 65536, Bias[wi], st[si], st[si] + 256, Gam[si], Bet[si],
            Cb, st[so], st[so] + 256, NN);
    };

    const int GMM = NN / 32;   // 3125 blocks, exact

    // ---- Layer 0 (h = x, f32): fused gather+GEMM1 -> z1 bf16 + stats0
    k_gathmm<0><<<GMM, 512, 0, stream>>>(x, rowptr, eidx,
                                         nullptr, nullptr, nullptr, nullptr,
                                         Wf + (size_t)0 * 65536, Bias[0],
                                         z1bf, st[0], st[0] + 256);
    gemm2(z1bf, 1, 0, 1, z2bf);

    // ---- Layer 1: fused gather(BN st1)+GEMM1(W2) -> z1 + stats2
    k_gathmm<1><<<GMM, 512, 0, stream>>>(z2bf, rowptr, eidx,
                                         st[1], st[1] + 256, Gam[1], Bet[1],
                                         Wf + (size_t)2 * 65536, Bias[2],
                                         z1bf, st[2], st[2] + 256);
    gemm2(z1bf, 3, 2, 3, z2bf);

    // ---- Layer 2: fused gather(BN st3)+GEMM1(W4) -> z1 + stats4
    k_gathmm<1><<<GMM, 512, 0, stream>>>(z2bf, rowptr, eidx,
                                         st[3], st[3] + 256, Gam[3], Bet[3],
                                         Wf + (size_t)4 * 65536, Bias[4],
                                         z1bf, st[4], st[4] + 256);
    // final: bf16 z1 + BN staged -> f32 OUT (no stats)
    k_gemm<true, false, false><<<1563, 256, 0, stream>>>(
        z1bf, Wf + (size_t)5 * 65536, Bias[5], st[4], st[4] + 256, Gam[4], Bet[4],
        OUT, nullptr, nullptr, NN);
}